// Round 1
// baseline (711.806 us; speedup 1.0000x reference)
//
#include <hip/hip_runtime.h>

typedef __attribute__((ext_vector_type(4))) float   f32x4;
typedef __attribute__((ext_vector_type(8))) __bf16  bf16x8;
typedef __attribute__((ext_vector_type(4))) __bf16  bf16x4;
typedef __attribute__((ext_vector_type(8))) unsigned short u16x8;

#define NH   16
#define HD   128
#define TSEQ 2048
#define DM   2048
#define MT   4096   // B*T rows

__device__ __forceinline__ f32x4 mfma_bf16(bf16x8 a, bf16x8 b, f32x4 c) {
  return __builtin_amdgcn_mfma_f32_16x16x32_bf16(a, b, c, 0, 0, 0);
}

// ---------------- f32 -> bf16 bulk convert ----------------
__global__ __launch_bounds__(256) void k_cvt(const float* __restrict__ s,
                                             __bf16* __restrict__ d, int n4) {
  int i = blockIdx.x * 256 + threadIdx.x;
  int stride = gridDim.x * 256;
  for (; i < n4; i += stride) {
    f32x4 v = ((const f32x4*)s)[i];
    bf16x4 o;
    o[0] = (__bf16)v[0]; o[1] = (__bf16)v[1];
    o[2] = (__bf16)v[2]; o[3] = (__bf16)v[3];
    ((bf16x4*)d)[i] = o;
  }
}

// ---------------- GEMM: C = A(MTxK) @ B^T (B is NxK row-major) ----------------
// MODE 0: write f32 to F (row-major MT x DM).
// MODE 1: blockIdx.z selects (B0,D0)/(B1,D1)/(B2,D2); write bf16 scattered to
//         (B,H,T,HD) layout: col -> (h,d), row -> (b,t).
template <int MODE>
__global__ __launch_bounds__(256) void k_gemm(
    const __bf16* __restrict__ A,
    const __bf16* __restrict__ B0, const __bf16* __restrict__ B1,
    const __bf16* __restrict__ B2,
    __bf16* __restrict__ D0, __bf16* __restrict__ D1, __bf16* __restrict__ D2,
    float* __restrict__ F) {
  __shared__ __bf16 As[128 * 40];   // rows padded to 40 bf16 (80B) -> 2-way banks
  __shared__ __bf16 Bs[128 * 40];

  const __bf16* __restrict__ Bm;
  __bf16* Dst = nullptr;
  if (MODE == 1) {
    int z = blockIdx.z;
    Bm  = (z == 0) ? B0 : (z == 1 ? B1 : B2);
    Dst = (z == 0) ? D0 : (z == 1 ? D1 : D2);
  } else {
    Bm = B0;
  }

  const int tid  = threadIdx.x;
  const int lane = tid & 63, w = tid >> 6;
  const int g    = lane >> 4, li = lane & 15;
  const int wr   = w >> 1, wc = w & 1;
  const int m0   = blockIdx.y * 128, n0 = blockIdx.x * 128;

  const f32x4 zero = {0.f, 0.f, 0.f, 0.f};
  f32x4 acc[4][4];
  for (int i = 0; i < 4; i++)
    for (int j = 0; j < 4; j++) acc[i][j] = zero;

  for (int k0 = 0; k0 < DM; k0 += 32) {
    for (int c = tid; c < 512; c += 256) {
      int row = c >> 2, seg = c & 3;
      *(bf16x8*)&As[row * 40 + seg * 8] =
          *(const bf16x8*)&A[(size_t)(m0 + row) * DM + k0 + seg * 8];
      *(bf16x8*)&Bs[row * 40 + seg * 8] =
          *(const bf16x8*)&Bm[(size_t)(n0 + row) * DM + k0 + seg * 8];
    }
    __syncthreads();
    bf16x8 af[4], bfr[4];
#pragma unroll
    for (int i = 0; i < 4; i++)
      af[i] = *(const bf16x8*)&As[(wr * 64 + i * 16 + li) * 40 + g * 8];
#pragma unroll
    for (int i = 0; i < 4; i++)
      bfr[i] = *(const bf16x8*)&Bs[(wc * 64 + i * 16 + li) * 40 + g * 8];
#pragma unroll
    for (int mi = 0; mi < 4; mi++)
#pragma unroll
      for (int ni = 0; ni < 4; ni++)
        acc[mi][ni] = mfma_bf16(af[mi], bfr[ni], acc[mi][ni]);
    __syncthreads();
  }

#pragma unroll
  for (int mi = 0; mi < 4; mi++)
#pragma unroll
    for (int ni = 0; ni < 4; ni++) {
      int colb = n0 + wc * 64 + ni * 16 + li;
#pragma unroll
      for (int r = 0; r < 4; r++) {
        int rowb = m0 + wr * 64 + mi * 16 + g * 4 + r;
        float vv = acc[mi][ni][r];
        if (MODE == 0) {
          F[(size_t)rowb * DM + colb] = vv;
        } else {
          int h = colb >> 7, d = colb & 127;
          int b = rowb >> 11, t = rowb & 2047;
          Dst[(((size_t)(b * NH + h)) * TSEQ + t) * HD + d] = (__bf16)vv;
        }
      }
    }
}

// ---------------- RoPE in-place on q and k (B,H,T,HD) ----------------
__global__ __launch_bounds__(256) void k_rope(__bf16* __restrict__ q,
                                              __bf16* __restrict__ kk,
                                              const float* __restrict__ rc,
                                              const float* __restrict__ rs) {
  int gid    = blockIdx.x * 256 + threadIdx.x;  // 2 * 32 * 2048 * 16 threads
  int tensor = gid >> 20;
  int rem    = gid & ((1 << 20) - 1);
  int bh     = rem >> 15;
  int r2     = rem & 32767;
  int t      = r2 >> 4;
  int j      = r2 & 15;
  int d0     = j * 4;
  __bf16* base = (tensor ? kk : q) + ((size_t)bh * TSEQ + t) * HD;
  f32x4 ca = *(const f32x4*)&rc[t * HD + d0];
  f32x4 cb = *(const f32x4*)&rc[t * HD + d0 + 64];
  f32x4 sa = *(const f32x4*)&rs[t * HD + d0];
  f32x4 sb = *(const f32x4*)&rs[t * HD + d0 + 64];
  bf16x4 xa = *(bf16x4*)&base[d0];
  bf16x4 xb = *(bf16x4*)&base[d0 + 64];
  bf16x4 oa, ob;
#pragma unroll
  for (int u = 0; u < 4; u++) {
    float fa = (float)xa[u], fb = (float)xb[u];
    oa[u] = (__bf16)(ca[u] * fa - fb * sa[u]);   // d < 64: rotated = -x[d+64]
    ob[u] = (__bf16)(cb[u] * fb + fa * sb[u]);   // d >= 64: rotated = x[d-64]
  }
  *(bf16x4*)&base[d0]      = oa;
  *(bf16x4*)&base[d0 + 64] = ob;
}

// ---------------- V (B,H,T,HD) -> Vt (B,H,HD,T) ----------------
__global__ __launch_bounds__(256) void k_trans(const __bf16* __restrict__ v,
                                               __bf16* __restrict__ vt) {
  __shared__ unsigned short tile[64][73];
  int bh = blockIdx.z;
  int t0 = blockIdx.x * 64, d0 = blockIdx.y * 64;
  int tid = threadIdx.x;
  int r = tid >> 2, s4 = tid & 3;
  const unsigned short* src =
      (const unsigned short*)v + ((size_t)bh * TSEQ + t0) * HD + d0;
  u16x8 a = *(const u16x8*)&src[(size_t)r * HD + s4 * 16];
  u16x8 b = *(const u16x8*)&src[(size_t)r * HD + s4 * 16 + 8];
#pragma unroll
  for (int u = 0; u < 8; u++) {
    tile[r][s4 * 16 + u]     = a[u];
    tile[r][s4 * 16 + 8 + u] = b[u];
  }
  __syncthreads();
  unsigned short* dst =
      (unsigned short*)vt + ((size_t)bh * HD + d0) * TSEQ + t0;
  u16x8 o1, o2;
#pragma unroll
  for (int u = 0; u < 8; u++) {
    o1[u] = tile[s4 * 16 + u][r];
    o2[u] = tile[s4 * 16 + 8 + u][r];
  }
  *(u16x8*)&dst[(size_t)r * TSEQ + s4 * 16]     = o1;
  *(u16x8*)&dst[(size_t)r * TSEQ + s4 * 16 + 8] = o2;
}

// ---------------- causal flash attention ----------------
// grid: (T/64, B*H). block: 256 (4 waves, 16 q-rows each). KB=32.
// q,k: (B,H,T,HD) roped bf16. vt: (B,H,HD,T). ctx out: (B,T,D) bf16.
__global__ __launch_bounds__(256) void k_attn(const __bf16* __restrict__ q,
                                              const __bf16* __restrict__ k,
                                              const __bf16* __restrict__ vt,
                                              __bf16* __restrict__ ctx) {
  __shared__ __bf16 Ks[32 * 136];   // rows padded to 272B -> 2-way banks
  __shared__ __bf16 Vs[128 * 40];   // Vt tile, rows padded to 80B
  __shared__ __bf16 Ps[4][16 * 40]; // per-wave P relayout buffer

  const int bh   = blockIdx.y;
  const int q0   = blockIdx.x * 64;
  const int tid  = threadIdx.x;
  const int lane = tid & 63, w = tid >> 6;
  const int g    = lane >> 4, li = lane & 15;
  const int qw   = q0 + w * 16;

  const __bf16* qb = q  + (size_t)bh * TSEQ * HD;
  const __bf16* kb = k  + (size_t)bh * TSEQ * HD;
  const __bf16* vb = vt + (size_t)bh * HD * TSEQ;

  bf16x8 qf[4];
#pragma unroll
  for (int kc = 0; kc < 4; kc++)
    qf[kc] = *(const bf16x8*)&qb[(size_t)(qw + li) * HD + kc * 32 + g * 8];

  const f32x4 zero = {0.f, 0.f, 0.f, 0.f};
  f32x4 o[8];
#pragma unroll
  for (int dt = 0; dt < 8; dt++) o[dt] = zero;
  float mrow[4] = {-1e30f, -1e30f, -1e30f, -1e30f};
  float lrow[4] = {0.f, 0.f, 0.f, 0.f};

  // scores scaled straight into log2 domain: s2 = s_raw * (1/sqrt(HD)) * log2(e)
  const float CST = 0.08838834764831845f * 1.4426950408889634f;
  const int nkt = (q0 + 64) >> 5;

  for (int kt = 0; kt < nkt; kt++) {
    const int kv0 = kt * 32;
    for (int c = tid; c < 512; c += 256) {      // K tile: 32 rows x 256B
      int row = c >> 4, seg = c & 15;
      *(bf16x8*)&Ks[row * 136 + seg * 8] =
          *(const bf16x8*)&kb[(size_t)(kv0 + row) * HD + seg * 8];
    }
    for (int c = tid; c < 512; c += 256) {      // Vt tile: 128 rows x 64B
      int row = c >> 2, seg = c & 3;
      *(bf16x8*)&Vs[row * 40 + seg * 8] =
          *(const bf16x8*)&vb[(size_t)row * TSEQ + kv0 + seg * 8];
    }
    __syncthreads();

    if (kv0 <= qw + 15) {                       // skip fully-masked tiles
      f32x4 s0 = zero, s1 = zero;
#pragma unroll
      for (int kc = 0; kc < 4; kc++) {
        bf16x8 k0f = *(const bf16x8*)&Ks[li * 136 + kc * 32 + g * 8];
        bf16x8 k1f = *(const bf16x8*)&Ks[(16 + li) * 136 + kc * 32 + g * 8];
        s0 = mfma_bf16(qf[kc], k0f, s0);
        s1 = mfma_bf16(qf[kc], k1f, s1);
      }
      float sv0[4], sv1[4], fac[4];
#pragma unroll
      for (int r = 0; r < 4; r++) {
        int qg  = qw + g * 4 + r;
        int kg0 = kv0 + li, kg1 = kv0 + 16 + li;
        sv0[r] = (kg0 <= qg) ? s0[r] * CST : -1e30f;
        sv1[r] = (kg1 <= qg) ? s1[r] * CST : -1e30f;
      }
#pragma unroll
      for (int r = 0; r < 4; r++) {
        float mt = fmaxf(sv0[r], sv1[r]);
        mt = fmaxf(mt, __shfl_xor(mt, 1));
        mt = fmaxf(mt, __shfl_xor(mt, 2));
        mt = fmaxf(mt, __shfl_xor(mt, 4));
        mt = fmaxf(mt, __shfl_xor(mt, 8));
        float mn = fmaxf(mrow[r], mt);
        fac[r]   = exp2f(mrow[r] - mn);
        float p0 = exp2f(sv0[r] - mn);
        float p1 = exp2f(sv1[r] - mn);
        float rsum = p0 + p1;
        rsum += __shfl_xor(rsum, 1);
        rsum += __shfl_xor(rsum, 2);
        rsum += __shfl_xor(rsum, 4);
        rsum += __shfl_xor(rsum, 8);
        lrow[r] = lrow[r] * fac[r] + rsum;
        mrow[r] = mn;
        Ps[w][(g * 4 + r) * 40 + li]      = (__bf16)p0;
        Ps[w][(g * 4 + r) * 40 + 16 + li] = (__bf16)p1;
      }
#pragma unroll
      for (int dt = 0; dt < 8; dt++) {
        o[dt][0] *= fac[0]; o[dt][1] *= fac[1];
        o[dt][2] *= fac[2]; o[dt][3] *= fac[3];
      }
      bf16x8 pa = *(const bf16x8*)&Ps[w][li * 40 + g * 8];
#pragma unroll
      for (int dt = 0; dt < 8; dt++) {
        bf16x8 vf = *(const bf16x8*)&Vs[(dt * 16 + li) * 40 + g * 8];
        o[dt] = mfma_bf16(pa, vf, o[dt]);
      }
    }
    __syncthreads();
  }

  const int b = bh >> 4, h = bh & 15;
#pragma unroll
  for (int r = 0; r < 4; r++) {
    float inv = 1.0f / lrow[r];
    size_t rowoff = ((size_t)(b * TSEQ + qw + g * 4 + r)) * DM + h * HD;
#pragma unroll
    for (int dt = 0; dt < 8; dt++)
      ctx[rowoff + dt * 16 + li] = (__bf16)(o[dt][r] * inv);
  }
}

// ---------------- launcher ----------------
extern "C" void kernel_launch(void* const* d_in, const int* in_sizes, int n_in,
                              void* d_out, int out_size, void* d_ws,
                              size_t ws_size, hipStream_t stream) {
  const float* x  = (const float*)d_in[0];
  const float* Wq = (const float*)d_in[1];
  const float* Wk = (const float*)d_in[2];
  const float* Wv = (const float*)d_in[3];
  const float* Wo = (const float*)d_in[4];
  const float* rc = (const float*)d_in[5];
  const float* rs = (const float*)d_in[6];
  float* out = (float*)d_out;

  // workspace carve (bf16), total ~117.4 MB
  __bf16* xb   = (__bf16*)d_ws;
  __bf16* wqb  = xb  + (size_t)MT * DM;
  __bf16* wkb  = wqb + (size_t)DM * DM;
  __bf16* wvb  = wkb + (size_t)DM * DM;
  __bf16* wob  = wvb + (size_t)DM * DM;
  __bf16* qbuf = wob + (size_t)DM * DM;
  __bf16* kbuf = qbuf + (size_t)MT * DM;
  __bf16* vbuf = kbuf + (size_t)MT * DM;
  __bf16* vtb  = vbuf + (size_t)MT * DM;
  __bf16* ctxb = vbuf;  // v dead after transpose; reuse for ctx

  k_cvt<<<2048, 256, 0, stream>>>(x,  xb,  (MT * DM) / 4);
  k_cvt<<<1024, 256, 0, stream>>>(Wq, wqb, (DM * DM) / 4);
  k_cvt<<<1024, 256, 0, stream>>>(Wk, wkb, (DM * DM) / 4);
  k_cvt<<<1024, 256, 0, stream>>>(Wv, wvb, (DM * DM) / 4);
  k_cvt<<<1024, 256, 0, stream>>>(Wo, wob, (DM * DM) / 4);

  dim3 gqkv(DM / 128, MT / 128, 3);
  k_gemm<1><<<gqkv, 256, 0, stream>>>(xb, wqb, wkb, wvb, qbuf, kbuf, vbuf,
                                      nullptr);
  k_rope<<<8192, 256, 0, stream>>>(qbuf, kbuf, rc, rs);

  dim3 gt(TSEQ / 64, HD / 64, 32);
  k_trans<<<gt, 256, 0, stream>>>(vbuf, vtb);

  dim3 ga(TSEQ / 64, 32);
  k_attn<<<ga, 256, 0, stream>>>(qbuf, kbuf, vtb, ctxb);

  dim3 go(DM / 128, MT / 128, 1);
  k_gemm<0><<<go, 256, 0, stream>>>(ctxb, wob, nullptr, nullptr, nullptr,
                                    nullptr, nullptr, out);
}

// Round 3
// 440.795 us; speedup vs baseline: 1.6148x; 1.6148x over previous
//
#include <hip/hip_runtime.h>

typedef __attribute__((ext_vector_type(4))) float   f32x4;
typedef __attribute__((ext_vector_type(8))) __bf16  bf16x8;
typedef __attribute__((ext_vector_type(4))) __bf16  bf16x4;
typedef __attribute__((ext_vector_type(8))) unsigned short u16x8;

#define NH   16
#define HD   128
#define TSEQ 2048
#define DM   2048
#define MT   4096   // B*T rows

__device__ __forceinline__ f32x4 mfma_bf16(bf16x8 a, bf16x8 b, f32x4 c) {
  return __builtin_amdgcn_mfma_f32_16x16x32_bf16(a, b, c, 0, 0, 0);
}

// async global->LDS, 16B per lane. LDS dest must be wave-uniform base;
// HW writes base + lane*16 (guide §5 / m97).
__device__ __forceinline__ void gl_lds16(const __bf16* g, __bf16* l) {
  __builtin_amdgcn_global_load_lds(
      (const __attribute__((address_space(1))) void*)g,
      (__attribute__((address_space(3))) void*)l, 16, 0, 0);
}

// ---------------- f32 -> bf16 bulk converts ----------------
__global__ __launch_bounds__(256) void k_cvt(const float* __restrict__ s,
                                             __bf16* __restrict__ d, int n4) {
  int i = blockIdx.x * 256 + threadIdx.x;
  int stride = gridDim.x * 256;
  for (; i < n4; i += stride) {
    f32x4 v = ((const f32x4*)s)[i];
    bf16x4 o;
    o[0] = (__bf16)v[0]; o[1] = (__bf16)v[1];
    o[2] = (__bf16)v[2]; o[3] = (__bf16)v[3];
    ((bf16x4*)d)[i] = o;
  }
}

__global__ __launch_bounds__(256) void k_cvtw(
    const float* __restrict__ W0, const float* __restrict__ W1,
    const float* __restrict__ W2, const float* __restrict__ W3,
    __bf16* __restrict__ D0, __bf16* __restrict__ D1,
    __bf16* __restrict__ D2, __bf16* __restrict__ D3, int n4) {
  int z = blockIdx.z;
  const float* s = (z == 0) ? W0 : (z == 1) ? W1 : (z == 2) ? W2 : W3;
  __bf16*      d = (z == 0) ? D0 : (z == 1) ? D1 : (z == 2) ? D2 : D3;
  int i = blockIdx.x * 256 + threadIdx.x;
  int stride = gridDim.x * 256;
  for (; i < n4; i += stride) {
    f32x4 v = ((const f32x4*)s)[i];
    bf16x4 o;
    o[0] = (__bf16)v[0]; o[1] = (__bf16)v[1];
    o[2] = (__bf16)v[2]; o[3] = (__bf16)v[3];
    ((bf16x4*)d)[i] = o;
  }
}

// ---------------- GEMM (m97 structure): C = A(MTxK) @ B^T ----------------
// 128x128 tile, BK=32, global_load_lds width-16 staging, linear LDS.
// MODE 0: write f32 to F. MODE 1: z selects (B,D) pair; scatter bf16 to
// (B,H,T,HD).
template <int MODE>
__global__ __launch_bounds__(256) void k_gemm(
    const __bf16* __restrict__ A,
    const __bf16* __restrict__ B0, const __bf16* __restrict__ B1,
    const __bf16* __restrict__ B2,
    __bf16* __restrict__ D0, __bf16* __restrict__ D1, __bf16* __restrict__ D2,
    float* __restrict__ F) {
  __shared__ __bf16 As[128 * 32];
  __shared__ __bf16 Bs[128 * 32];

  const __bf16* __restrict__ Bm;
  __bf16* Dst = nullptr;
  if (MODE == 1) {
    int z = blockIdx.z;
    Bm  = (z == 0) ? B0 : (z == 1 ? B1 : B2);
    Dst = (z == 0) ? D0 : (z == 1 ? D1 : D2);
  } else {
    Bm = B0;
  }

  // XCD-chunked swizzle over 512 wgs (nwg%8==0 -> bijective)
  const int bid = blockIdx.x;
  const int wg  = (bid & 7) * 64 + (bid >> 3);
  const int n0  = (wg & 15) * 128;
  const int m0  = (wg >> 4) * 128;

  const int tid  = threadIdx.x;
  const int lane = tid & 63, w = tid >> 6;
  const int g    = lane >> 4, li = lane & 15;
  const int wr   = w >> 1, wc = w & 1;
  const int srow = lane >> 2;   // staging: row within 16-row chunk
  const int sseg = lane & 3;    // staging: 16B segment within 64B row-part

  const f32x4 zero = {0.f, 0.f, 0.f, 0.f};
  f32x4 acc[4][4];
#pragma unroll
  for (int i = 0; i < 4; i++)
#pragma unroll
    for (int j = 0; j < 4; j++) acc[i][j] = zero;

  for (int k0 = 0; k0 < DM; k0 += 32) {
#pragma unroll
    for (int c = 0; c < 2; c++) {
      const int ch = w * 2 + c;  // 8 chunks of 16 rows each
      gl_lds16(&A[(size_t)(m0 + ch * 16 + srow) * DM + k0 + sseg * 8],
               &As[ch * 512]);
      gl_lds16(&Bm[(size_t)(n0 + ch * 16 + srow) * DM + k0 + sseg * 8],
               &Bs[ch * 512]);
    }
    __syncthreads();
    bf16x8 af[4], bfr[4];
#pragma unroll
    for (int i = 0; i < 4; i++)
      af[i] = *(const bf16x8*)&As[(wr * 64 + i * 16 + li) * 32 + g * 8];
#pragma unroll
    for (int i = 0; i < 4; i++)
      bfr[i] = *(const bf16x8*)&Bs[(wc * 64 + i * 16 + li) * 32 + g * 8];
#pragma unroll
    for (int mi = 0; mi < 4; mi++)
#pragma unroll
      for (int ni = 0; ni < 4; ni++)
        acc[mi][ni] = mfma_bf16(af[mi], bfr[ni], acc[mi][ni]);
    __syncthreads();
  }

#pragma unroll
  for (int mi = 0; mi < 4; mi++)
#pragma unroll
    for (int ni = 0; ni < 4; ni++) {
      int colb = n0 + wc * 64 + ni * 16 + li;
#pragma unroll
      for (int r = 0; r < 4; r++) {
        int rowb = m0 + wr * 64 + mi * 16 + g * 4 + r;
        float vv = acc[mi][ni][r];
        if (MODE == 0) {
          F[(size_t)rowb * DM + colb] = vv;
        } else {
          int h = colb >> 7, d = colb & 127;
          int b = rowb >> 11, t = rowb & 2047;
          Dst[(((size_t)(b * NH + h)) * TSEQ + t) * HD + d] = (__bf16)vv;
        }
      }
    }
}

// ---------------- RoPE in-place on q and k (B,H,T,HD) ----------------
__global__ __launch_bounds__(256) void k_rope(__bf16* __restrict__ q,
                                              __bf16* __restrict__ kk,
                                              const float* __restrict__ rc,
                                              const float* __restrict__ rs) {
  int gid    = blockIdx.x * 256 + threadIdx.x;
  int tensor = gid >> 20;
  int rem    = gid & ((1 << 20) - 1);
  int bh     = rem >> 15;
  int r2     = rem & 32767;
  int t      = r2 >> 4;
  int j      = r2 & 15;
  int d0     = j * 4;
  __bf16* base = (tensor ? kk : q) + ((size_t)bh * TSEQ + t) * HD;
  f32x4 ca = *(const f32x4*)&rc[t * HD + d0];
  f32x4 cb = *(const f32x4*)&rc[t * HD + d0 + 64];
  f32x4 sa = *(const f32x4*)&rs[t * HD + d0];
  f32x4 sb = *(const f32x4*)&rs[t * HD + d0 + 64];
  bf16x4 xa = *(bf16x4*)&base[d0];
  bf16x4 xb = *(bf16x4*)&base[d0 + 64];
  bf16x4 oa, ob;
#pragma unroll
  for (int u = 0; u < 4; u++) {
    float fa = (float)xa[u], fb = (float)xb[u];
    oa[u] = (__bf16)(ca[u] * fa - fb * sa[u]);
    ob[u] = (__bf16)(cb[u] * fb + fa * sb[u]);
  }
  *(bf16x4*)&base[d0]      = oa;
  *(bf16x4*)&base[d0 + 64] = ob;
}

// ---------------- V (B,H,T,HD) -> Vt (B,H,HD,T) ----------------
__global__ __launch_bounds__(256) void k_trans(const __bf16* __restrict__ v,
                                               __bf16* __restrict__ vt) {
  __shared__ unsigned short tile[64][73];
  int bh = blockIdx.z;
  int t0 = blockIdx.x * 64, d0 = blockIdx.y * 64;
  int tid = threadIdx.x;
  int r = tid >> 2, s4 = tid & 3;
  const unsigned short* src =
      (const unsigned short*)v + ((size_t)bh * TSEQ + t0) * HD + d0;
  u16x8 a = *(const u16x8*)&src[(size_t)r * HD + s4 * 16];
  u16x8 b = *(const u16x8*)&src[(size_t)r * HD + s4 * 16 + 8];
#pragma unroll
  for (int u = 0; u < 8; u++) {
    tile[r][s4 * 16 + u]     = a[u];
    tile[r][s4 * 16 + 8 + u] = b[u];
  }
  __syncthreads();
  unsigned short* dst =
      (unsigned short*)vt + ((size_t)bh * HD + d0) * TSEQ + t0;
  u16x8 o1, o2;
#pragma unroll
  for (int u = 0; u < 8; u++) {
    o1[u] = tile[s4 * 16 + u][r];
    o2[u] = tile[s4 * 16 + 8 + u][r];
  }
  *(u16x8*)&dst[(size_t)r * TSEQ + s4 * 16]     = o1;
  *(u16x8*)&dst[(size_t)r * TSEQ + s4 * 16 + 8] = o2;
}

// ---------------- causal flash attention ----------------
// QBLK=128 (4 waves x 32 q-rows), KVBLK=64. K,V staged in LDS with T14
// async-split (global->reg early, ds_write late). P relayout via per-wave
// LDS slab. Reversed q-tile order + XCD-chunked swizzle for balance/L2.
__global__ __launch_bounds__(256, 2) void k_attn(const __bf16* __restrict__ q,
                                                 const __bf16* __restrict__ k,
                                                 const __bf16* __restrict__ vt,
                                                 __bf16* __restrict__ ctx) {
  __shared__ __bf16 Ks[64 * 136];   // [kv][128 +8 pad] rows = 272B
  __shared__ __bf16 Vs[128 * 72];   // [d][64 +8 pad]   rows = 144B
  __shared__ __bf16 Ps[4][32 * 72]; // per-wave P: [32 q][64 +8 pad]

  const int bid = blockIdx.x;
  const int wg  = (bid & 7) * 64 + (bid >> 3);  // XCD chunking: 4 bh per XCD
  const int bh  = wg >> 4;
  const int qt  = 15 - (wg & 15);               // heavy tiles first
  const int q0  = qt * 128;

  const int tid  = threadIdx.x;
  const int lane = tid & 63, w = tid >> 6;
  const int g    = lane >> 4, li = lane & 15;
  const int qw   = q0 + w * 32;

  const __bf16* qb = q  + (size_t)bh * TSEQ * HD;
  const __bf16* kb = k  + (size_t)bh * TSEQ * HD;
  const __bf16* vb = vt + (size_t)bh * HD * TSEQ;

  // fold 1/sqrt(HD) * log2(e) into Q fragments
  const float CST = 0.08838834764831845f * 1.4426950408889634f;
  bf16x8 qf[2][4];
#pragma unroll
  for (int s = 0; s < 2; s++)
#pragma unroll
    for (int kc = 0; kc < 4; kc++) {
      bf16x8 t =
          *(const bf16x8*)&qb[(size_t)(qw + s * 16 + li) * HD + kc * 32 + g * 8];
      bf16x8 o;
#pragma unroll
      for (int e = 0; e < 8; e++) o[e] = (__bf16)((float)t[e] * CST);
      qf[s][kc] = o;
    }

  const f32x4 zero = {0.f, 0.f, 0.f, 0.f};
  f32x4 o[2][8];
#pragma unroll
  for (int s = 0; s < 2; s++)
#pragma unroll
    for (int dt = 0; dt < 8; dt++) o[s][dt] = zero;
  float mrow[2][4], lrow[2][4];
#pragma unroll
  for (int s = 0; s < 2; s++)
#pragma unroll
    for (int r = 0; r < 4; r++) { mrow[s][r] = -1e30f; lrow[s][r] = 0.f; }

  const int nkt = 2 * qt + 2;

  // staging assignment (per thread, 4 chunks of 16B each for K and V)
  const int kR = tid >> 4, kS = tid & 15;  // K rows kR+16i, seg kS
  const int vR = tid >> 3, vS = tid & 7;   // V rows vR+32i, seg vS

  bf16x8 pk[4], pv[4];
#pragma unroll
  for (int i = 0; i < 4; i++) {
    pk[i] = *(const bf16x8*)&kb[(size_t)(kR + 16 * i) * HD + kS * 8];
    pv[i] = *(const bf16x8*)&vb[(size_t)(vR + 32 * i) * TSEQ + vS * 8];
  }

  for (int kt = 0; kt < nkt; kt++) {
    const int kv0 = kt * 64;
    __syncthreads();  // prev-iter LDS reads done
#pragma unroll
    for (int i = 0; i < 4; i++)
      *(bf16x8*)&Ks[(kR + 16 * i) * 136 + kS * 8] = pk[i];
#pragma unroll
    for (int i = 0; i < 4; i++)
      *(bf16x8*)&Vs[(vR + 32 * i) * 72 + vS * 8] = pv[i];
    if (kt + 1 < nkt) {  // T14: issue next tile's loads; land during compute
      const int nv0 = kv0 + 64;
#pragma unroll
      for (int i = 0; i < 4; i++) {
        pk[i] = *(const bf16x8*)&kb[(size_t)(nv0 + kR + 16 * i) * HD + kS * 8];
        pv[i] = *(const bf16x8*)&vb[(size_t)(vR + 32 * i) * TSEQ + nv0 + vS * 8];
      }
    }
    __syncthreads();  // staging visible

    if (kv0 <= qw + 31) {
      // ---- QK^T: 32 q-rows x 64 kv, K=128 ----
      f32x4 sc[2][4];
#pragma unroll
      for (int s = 0; s < 2; s++)
#pragma unroll
        for (int kvf = 0; kvf < 4; kvf++) sc[s][kvf] = zero;
#pragma unroll
      for (int kvf = 0; kvf < 4; kvf++)
#pragma unroll
        for (int kc = 0; kc < 4; kc++) {
          bf16x8 kf =
              *(const bf16x8*)&Ks[(kvf * 16 + li) * 136 + kc * 32 + g * 8];
          sc[0][kvf] = mfma_bf16(qf[0][kc], kf, sc[0][kvf]);
          sc[1][kvf] = mfma_bf16(qf[1][kc], kf, sc[1][kvf]);
        }
      // ---- causal mask (only diagonal-overlap tiles) ----
      if (kv0 + 63 > qw) {
#pragma unroll
        for (int s = 0; s < 2; s++)
#pragma unroll
          for (int kvf = 0; kvf < 4; kvf++) {
            int kg = kv0 + kvf * 16 + li;
#pragma unroll
            for (int r = 0; r < 4; r++) {
              int qg = qw + s * 16 + g * 4 + r;
              if (kg > qg) sc[s][kvf][r] = -1e30f;
            }
          }
      }
      // ---- online softmax: row max (shfl over li only) ----
      float mnew[2][4];
      bool upd = false;
#pragma unroll
      for (int s = 0; s < 2; s++)
#pragma unroll
        for (int r = 0; r < 4; r++) {
          float a = fmaxf(fmaxf(sc[s][0][r], sc[s][1][r]),
                          fmaxf(sc[s][2][r], sc[s][3][r]));
          a = fmaxf(a, __shfl_xor(a, 1));
          a = fmaxf(a, __shfl_xor(a, 2));
          a = fmaxf(a, __shfl_xor(a, 4));
          a = fmaxf(a, __shfl_xor(a, 8));
          mnew[s][r] = fmaxf(mrow[s][r], a);
          upd = upd || (a > mrow[s][r]);
        }
      if (__any(upd)) {  // exact defer: skip rescale when no max grew
#pragma unroll
        for (int s = 0; s < 2; s++)
#pragma unroll
          for (int r = 0; r < 4; r++) {
            float fac = __builtin_amdgcn_exp2f(mrow[s][r] - mnew[s][r]);
            mrow[s][r] = mnew[s][r];
            lrow[s][r] *= fac;
#pragma unroll
            for (int dt = 0; dt < 8; dt++) o[s][dt][r] *= fac;
          }
      }
      // ---- P = exp2(s - m); lane-partial l; write Ps ----
#pragma unroll
      for (int s = 0; s < 2; s++)
#pragma unroll
        for (int kvf = 0; kvf < 4; kvf++) {
#pragma unroll
          for (int r = 0; r < 4; r++) {
            float p = __builtin_amdgcn_exp2f(sc[s][kvf][r] - mrow[s][r]);
            lrow[s][r] += p;
            Ps[w][(s * 16 + g * 4 + r) * 72 + kvf * 16 + li] = (__bf16)p;
          }
        }
      // ---- PV: read P as A-frags, V as B-frags ----
      bf16x8 pa[2][2];
#pragma unroll
      for (int s = 0; s < 2; s++)
#pragma unroll
        for (int kvs = 0; kvs < 2; kvs++)
          pa[s][kvs] =
              *(const bf16x8*)&Ps[w][(s * 16 + li) * 72 + kvs * 32 + g * 8];
#pragma unroll
      for (int dt = 0; dt < 8; dt++) {
        bf16x8 v0 = *(const bf16x8*)&Vs[(dt * 16 + li) * 72 + g * 8];
        bf16x8 v1 = *(const bf16x8*)&Vs[(dt * 16 + li) * 72 + 32 + g * 8];
        o[0][dt] = mfma_bf16(pa[0][0], v0, o[0][dt]);
        o[0][dt] = mfma_bf16(pa[0][1], v1, o[0][dt]);
        o[1][dt] = mfma_bf16(pa[1][0], v0, o[1][dt]);
        o[1][dt] = mfma_bf16(pa[1][1], v1, o[1][dt]);
      }
    }
  }

  // ---- epilogue: reduce lane-partial l over li, scale, write ----
  const int b = bh >> 4, h = bh & 15;
#pragma unroll
  for (int s = 0; s < 2; s++)
#pragma unroll
    for (int r = 0; r < 4; r++) {
      float l = lrow[s][r];
      l += __shfl_xor(l, 1);
      l += __shfl_xor(l, 2);
      l += __shfl_xor(l, 4);
      l += __shfl_xor(l, 8);
      float inv = 1.0f / l;
      size_t rowoff =
          ((size_t)(b * TSEQ + qw + s * 16 + g * 4 + r)) * DM + h * HD;
#pragma unroll
      for (int dt = 0; dt < 8; dt++)
        ctx[rowoff + dt * 16 + li] = (__bf16)(o[s][dt][r] * inv);
    }
}

// ---------------- launcher ----------------
extern "C" void kernel_launch(void* const* d_in, const int* in_sizes, int n_in,
                              void* d_out, int out_size, void* d_ws,
                              size_t ws_size, hipStream_t stream) {
  const float* x  = (const float*)d_in[0];
  const float* Wq = (const float*)d_in[1];
  const float* Wk = (const float*)d_in[2];
  const float* Wv = (const float*)d_in[3];
  const float* Wo = (const float*)d_in[4];
  const float* rc = (const float*)d_in[5];
  const float* rs = (const float*)d_in[6];
  float* out = (float*)d_out;

  __bf16* xb   = (__bf16*)d_ws;
  __bf16* wqb  = xb  + (size_t)MT * DM;
  __bf16* wkb  = wqb + (size_t)DM * DM;
  __bf16* wvb  = wkb + (size_t)DM * DM;
  __bf16* wob  = wvb + (size_t)DM * DM;
  __bf16* qbuf = wob + (size_t)DM * DM;
  __bf16* kbuf = qbuf + (size_t)MT * DM;
  __bf16* vbuf = kbuf + (size_t)MT * DM;
  __bf16* vtb  = vbuf + (size_t)MT * DM;
  __bf16* ctxb = vbuf;  // v dead after transpose; reuse for ctx

  k_cvt<<<2048, 256, 0, stream>>>(x, xb, (MT * DM) / 4);
  dim3 gw(1024, 1, 4);
  k_cvtw<<<gw, 256, 0, stream>>>(Wq, Wk, Wv, Wo, wqb, wkb, wvb, wob,
                                 (DM * DM) / 4);

  dim3 gqkv(512, 1, 3);
  k_gemm<1><<<gqkv, 256, 0, stream>>>(xb, wqb, wkb, wvb, qbuf, kbuf, vbuf,
                                      nullptr);
  k_rope<<<8192, 256, 0, stream>>>(qbuf, kbuf, rc, rs);

  dim3 gt(TSEQ / 64, HD / 64, 32);
  k_trans<<<gt, 256, 0, stream>>>(vbuf, vtb);

  k_attn<<<512, 256, 0, stream>>>(qbuf, kbuf, vtb, ctxb);

  dim3 go(512, 1, 1);
  k_gemm<0><<<go, 256, 0, stream>>>(ctxb, wob, nullptr, nullptr, nullptr,
                                    nullptr, nullptr, out);
}